// Round 15
// baseline (528.804 us; speedup 1.0000x reference)
//
#include <hip/hip_runtime.h>
#include <hip/hip_bf16.h>
#include <stdint.h>

typedef __attribute__((ext_vector_type(8))) short short8;
typedef __attribute__((ext_vector_type(4))) float f32x4;

#define DEVI __device__ __forceinline__

DEVI unsigned short f2bf(float f) {
  union { float f; unsigned int u; } c; c.f = f;
  unsigned int u = c.u;
  u += 0x7fffu + ((u >> 16) & 1u);   // round-to-nearest-even
  return (unsigned short)(u >> 16);
}

DEVI void gl_lds16(const void* gsrc, void* lds) {
  __builtin_amdgcn_global_load_lds(
      (const __attribute__((address_space(1))) unsigned int*)gsrc,
      (__attribute__((address_space(3))) unsigned int*)lds, 16, 0, 0);
}

#define MFMA(a, b, c) __builtin_amdgcn_mfma_f32_16x16x32_bf16((a), (b), (c), 0, 0, 0)
#define BAR()  __builtin_amdgcn_s_barrier()
#define SCHED0() __builtin_amdgcn_sched_barrier(0)

// ---------------- merged fp32 -> bf16 convert: x (4 quarters) + 4 weights ----------------
__global__ void cvt_all(const float* __restrict__ x, unsigned short* __restrict__ xb,
                        const float* __restrict__ w0, const float* __restrict__ w1,
                        const float* __restrict__ w2, const float* __restrict__ w3,
                        unsigned short* __restrict__ o0, unsigned short* __restrict__ o1,
                        unsigned short* __restrict__ o2, unsigned short* __restrict__ o3) {
  const int sel = blockIdx.y;
  const float* in;
  unsigned short* out;
  if (sel < 4) { in = x + (size_t)sel * 4194304; out = xb + (size_t)sel * 4194304; }
  else if (sel == 4) { in = w0; out = o0; }
  else if (sel == 5) { in = w1; out = o1; }
  else if (sel == 6) { in = w2; out = o2; }
  else               { in = w3; out = o3; }
  const int stride = gridDim.x * blockDim.x;
  for (int i = blockIdx.x * blockDim.x + threadIdx.x; i < 1048576; i += stride) {
    const float4 v = ((const float4*)in)[i];
    ushort4 o;
    o.x = f2bf(v.x); o.y = f2bf(v.y); o.z = f2bf(v.z); o.w = f2bf(v.w);
    ((ushort4*)out)[i] = o;
  }
}

// Fragment-packed layouts (per head, T=2048, HD=128, 262144 elems):
//  QK-pack:  off(t,e) = (t>>4)*2048 + (e>>5)*512 + (t&15)*32 + (e&31)
//  V-pack:   off(d,t) = (t>>6)*8192 + (d>>4)*1024 + ((t>>5)&1)*512 + (d&15)*32 + (t&31)

// ---------------- 256x256 8-phase bf16 GEMM (r9, best) ----------------
template<int MODE>
__global__ __launch_bounds__(512, 2)
void gemm8p(const unsigned short* __restrict__ A,
            const unsigned short* __restrict__ Bw,
            const float* __restrict__ bq,
            const float* __restrict__ bk,
            const float* __restrict__ bv,
            float* __restrict__ Kf,
            float* __restrict__ Vf,
            unsigned short* __restrict__ Qpk,
            unsigned short* __restrict__ Kpk,
            unsigned short* __restrict__ Vpk,
            float* __restrict__ Cf,
            int M, int N, int K)
{
  __shared__ unsigned short S[2][32768];   // per buf: A frags [0,16384), B [16384,32768)
  const int tid  = threadIdx.x;
  const int lane = tid & 63;
  const int wid  = tid >> 6;
  const int l15  = lane & 15, l4 = lane >> 4;
  const int wm   = wid >> 2, wn = wid & 3;

  const int chunk = gridDim.x >> 3;
  const int q  = blockIdx.x;
  const int wg = (q & 7) * chunk + (q >> 3);
  const int bm = (wg & 31) * 256;
  const int bn = (wg >> 5) * 256;

  const unsigned short* Asrc = A  + (size_t)(bm + (wid >> 1) * 16 + l15) * K + (wid & 1) * 32 + l4 * 8;
  const unsigned short* Bsrc = Bw + (size_t)(bn + (wid >> 1) * 16 + l15) * K + (wid & 1) * 32 + l4 * 8;

  const int nKt   = K >> 6;
  const int HTmax = nKt * 4;

  auto stage_ht = [&](int g) {
    if (g >= HTmax) return;
    const int t = g >> 2, sub = g & 3, buf = t & 1, k0 = t << 6;
#pragma unroll
    for (int cc = 0; cc < 2; ++cc) {
      if (sub >= 2) {
        const int c = (sub - 2) * 2 + cc;
        gl_lds16(Asrc + (size_t)(c * 64) * K + k0,
                 &S[buf][c * 4096 + wid * 512 + lane * 8]);
      } else {
        const int c = sub * 2 + cc;
        gl_lds16(Bsrc + (size_t)(c * 64) * K + k0,
                 &S[buf][16384 + c * 4096 + wid * 512 + lane * 8]);
      }
    }
  };

#pragma unroll
  for (int g = 0; g < 7; ++g) stage_ht(g);
  asm volatile("s_waitcnt vmcnt(6)" ::: "memory");
  SCHED0();
  BAR();

  f32x4 acc[8][4] = {};
  short8 a[4][2], b[4][2];

  for (int t = 0; t < nKt; ++t) {
    const unsigned short* Sb = S[t & 1];
    const int P = t * 4;

#pragma unroll
    for (int i = 0; i < 4; ++i)
#pragma unroll
      for (int ks = 0; ks < 2; ++ks)
        a[i][ks] = *(const short8*)&Sb[((wm * 8 + i) * 2 + ks) * 512 + lane * 8];
#pragma unroll
    for (int j = 0; j < 4; ++j)
#pragma unroll
      for (int ks = 0; ks < 2; ++ks)
        b[j][ks] = *(const short8*)&Sb[16384 + ((wn * 4 + j) * 2 + ks) * 512 + lane * 8];
    stage_ht(P + 7);
    BAR();
    asm volatile("s_waitcnt lgkmcnt(0)" ::: "memory");
    SCHED0();
    __builtin_amdgcn_s_setprio(1);
#pragma unroll
    for (int i = 0; i < 4; ++i)
#pragma unroll
      for (int j = 0; j < 2; ++j)
#pragma unroll
        for (int ks = 0; ks < 2; ++ks)
          acc[i][j] = MFMA(a[i][ks], b[j][ks], acc[i][j]);
    __builtin_amdgcn_s_setprio(0);
    BAR();

    stage_ht(P + 8);
    BAR();
    __builtin_amdgcn_s_setprio(1);
#pragma unroll
    for (int i = 0; i < 4; ++i)
#pragma unroll
      for (int j = 0; j < 2; ++j)
#pragma unroll
        for (int ks = 0; ks < 2; ++ks)
          acc[i][2 + j] = MFMA(a[i][ks], b[2 + j][ks], acc[i][2 + j]);
    __builtin_amdgcn_s_setprio(0);
    BAR();

#pragma unroll
    for (int i = 0; i < 4; ++i)
#pragma unroll
      for (int ks = 0; ks < 2; ++ks)
        a[i][ks] = *(const short8*)&Sb[((wm * 8 + 4 + i) * 2 + ks) * 512 + lane * 8];
    stage_ht(P + 9);
    BAR();
    asm volatile("s_waitcnt lgkmcnt(0)" ::: "memory");
    SCHED0();
    __builtin_amdgcn_s_setprio(1);
#pragma unroll
    for (int i = 0; i < 4; ++i)
#pragma unroll
      for (int j = 0; j < 2; ++j)
#pragma unroll
        for (int ks = 0; ks < 2; ++ks)
          acc[4 + i][j] = MFMA(a[i][ks], b[j][ks], acc[4 + i][j]);
    __builtin_amdgcn_s_setprio(0);
    BAR();

    stage_ht(P + 10);
    if (t < nKt - 2)       { asm volatile("s_waitcnt vmcnt(6)" ::: "memory"); SCHED0(); }
    else if (t == nKt - 2) { asm volatile("s_waitcnt vmcnt(0)" ::: "memory"); SCHED0(); }
    BAR();
    __builtin_amdgcn_s_setprio(1);
#pragma unroll
    for (int i = 0; i < 4; ++i)
#pragma unroll
      for (int j = 0; j < 2; ++j)
#pragma unroll
        for (int ks = 0; ks < 2; ++ks)
          acc[4 + i][2 + j] = MFMA(a[i][ks], b[2 + j][ks], acc[4 + i][2 + j]);
    __builtin_amdgcn_s_setprio(0);
    BAR();
  }

  // ---- epilogue ----
  const int rbase = l4 * 4;
#pragma unroll
  for (int m = 0; m < 8; ++m) {
    const int row0 = bm + wm * 128 + m * 16 + rbase;
#pragma unroll
    for (int n = 0; n < 4; ++n) {
      const int col6 = bn + wn * 64 + n * 16 + l15;
      if constexpr (MODE == 3) {
        const float bb = bq[col6];
#pragma unroll
        for (int r = 0; r < 4; ++r)
          Cf[(size_t)(row0 + r) * N + col6] = acc[m][n][r] + bb;
      } else {
        const int sel = col6 >> 11;
        const int col = col6 & 2047;
        const float bb = (sel == 0 ? bq : sel == 1 ? bk : bv)[col];
        float vv[4];
#pragma unroll
        for (int r = 0; r < 4; ++r) vv[r] = acc[m][n][r] + bb;
        const int bI = row0 >> 11, t0 = row0 & 2047;
        const int h = col >> 7, e = col & 127;
        const size_t hb = ((size_t)(bI * 16 + h)) * 262144;
        if (sel == 0) {
          const size_t qb = hb + (size_t)(t0 >> 4) * 2048 + (e >> 5) * 512
                          + (t0 & 15) * 32 + (e & 31);
#pragma unroll
          for (int r = 0; r < 4; ++r) Qpk[qb + (size_t)r * 32] = f2bf(vv[r]);
        } else if (sel == 1) {
          const size_t idx = hb + (size_t)t0 * 128 + e;
          const size_t qb = hb + (size_t)(t0 >> 4) * 2048 + (e >> 5) * 512
                          + (t0 & 15) * 32 + (e & 31);
#pragma unroll
          for (int r = 0; r < 4; ++r) {
            Kf[idx + (size_t)r * 128] = vv[r];
            Kpk[qb + (size_t)r * 32] = f2bf(vv[r]);
          }
        } else {
          const size_t idx = hb + (size_t)t0 * 128 + e;
#pragma unroll
          for (int r = 0; r < 4; ++r) Vf[idx + (size_t)r * 128] = vv[r];
          const size_t vb = hb + (size_t)(t0 >> 6) * 8192 + (size_t)(e >> 4) * 1024
                          + ((t0 >> 5) & 1) * 512 + (e & 15) * 32 + (t0 & 31);
          ushort4 pk;
          pk.x = f2bf(vv[0]); pk.y = f2bf(vv[1]);
          pk.z = f2bf(vv[2]); pk.w = f2bf(vv[3]);
          *(ushort4*)&Vpk[vb] = pk;
        }
      }
    }
  }
}

// ---------------- causal flash attention: near-balanced single-strip waves ----------------
// 1024 blocks x 256 threads (4 waves), each wave handles ONE 32-row q-strip.
// Block = 4 consecutive strips {4*sg4 .. 4*sg4+3} of one head -> intra-block
// wave lengths differ by <= 1 tile. 1024 blocks = 4 blocks/CU capacity
// (VGPR ~124 <= 128 -> 4 waves/SIMD; LDS 18KB x 4 fits) -> up to 16 waves/CU,
// double r11's residency. Heavy strip-groups dispatched first; same-head
// blocks pinned to one XCD (bid&7) for K/V L2 locality. Barrier-free.
__global__ __launch_bounds__(256, 2)
void attn_fwd(const unsigned short* __restrict__ Qf,
              const unsigned short* __restrict__ Kf,
              const unsigned short* __restrict__ Vf,
              unsigned short* __restrict__ Ab)
{
  constexpr float scale = 0.08838834764831843f;  // 1/sqrt(128)
  __shared__ unsigned short Pl[4][32][72];

  const int bid = blockIdx.x;                    // 0..1023
  const int bh  = (bid & 7) * 8 + ((bid >> 3) & 7);  // head; same head -> same XCD
  const int sg4 = 15 - (bid >> 6);               // strip-group, heavy first
  const int tid = threadIdx.x;
  const int wid = tid >> 6, lane = tid & 63;
  const int strip = sg4 * 4 + wid;               // 0..63
  const int qw = strip * 32;
  const int bI = bh >> 4, h = bh & 15;
  const int lr = lane & 15, lg = lane >> 4;
  const int lfo = lr * 32 + lg * 8;              // per-lane offset within 1KB frag

  const unsigned short* Qp = Qf + (size_t)bh * 262144 + (size_t)(qw >> 4) * 2048;
  const unsigned short* Kp = Kf + (size_t)bh * 262144;
  const unsigned short* Vp = Vf + (size_t)bh * 262144;

  short8 qf[2][4];
#pragma unroll
  for (int m = 0; m < 2; ++m)
#pragma unroll
    for (int ks = 0; ks < 4; ++ks)
      qf[m][ks] = *(const short8*)&Qp[m * 2048 + ks * 512 + lfo];

  f32x4 o[2][8] = {};
  float mrun[2][4], lrun[2][4];
#pragma unroll
  for (int m = 0; m < 2; ++m)
#pragma unroll
    for (int r = 0; r < 4; ++r) { mrun[m][r] = -1e30f; lrun[m][r] = 0.f; }

  const int nfull = qw >> 6;                     // tiles before the diagonal tile
  for (int kt = 0; kt <= nfull; ++kt) {
    const int kv0 = kt * 64;
    const bool diag = (kt == nfull);
    const unsigned short* Kt = Kp + (size_t)(kv0 >> 4) * 2048;
    const unsigned short* Vt = Vp + (size_t)(kv0 >> 6) * 8192;

    // ---- S = Q K^T : 16 coalesced K-frag loads, then 32 MFMA ----
    short8 kf[4][4];
#pragma unroll
    for (int n = 0; n < 4; ++n)
#pragma unroll
      for (int ks = 0; ks < 4; ++ks)
        kf[n][ks] = *(const short8*)&Kt[n * 2048 + ks * 512 + lfo];
    f32x4 s[2][4] = {};
    __builtin_amdgcn_s_setprio(1);
#pragma unroll
    for (int ks = 0; ks < 4; ++ks)
#pragma unroll
      for (int m = 0; m < 2; ++m)
#pragma unroll
        for (int n = 0; n < 4; ++n)
          s[m][n] = MFMA(qf[m][ks], kf[n][ks], s[m][n]);
    __builtin_amdgcn_s_setprio(0);

    // ---- issue all V-frag loads; latency hides under softmax ----
    short8 vf[2][8];
#pragma unroll
    for (int ks2 = 0; ks2 < 2; ++ks2)
#pragma unroll
      for (int dt = 0; dt < 8; ++dt)
        vf[ks2][dt] = *(const short8*)&Vt[dt * 1024 + ks2 * 512 + lfo];

    // ---- scale (+ mask on diagonal tile) + tile row-max ----
    float tmax[2][4];
#pragma unroll
    for (int m = 0; m < 2; ++m)
#pragma unroll
      for (int r = 0; r < 4; ++r) tmax[m][r] = -1e30f;
#pragma unroll
    for (int m = 0; m < 2; ++m)
#pragma unroll
      for (int n = 0; n < 4; ++n) {
        const int kg = kv0 + n * 16 + lr;
#pragma unroll
        for (int r = 0; r < 4; ++r) {
          float sv = s[m][n][r] * scale;
          if (diag) {
            const int qg = qw + m * 16 + lg * 4 + r;
            sv = (kg <= qg) ? sv : -1e30f;
          }
          s[m][n][r] = sv;
          tmax[m][r] = fmaxf(tmax[m][r], sv);
        }
      }
    // ---- reduce tile max across the 16-lane row groups ----
#pragma unroll
    for (int m = 0; m < 2; ++m)
#pragma unroll
      for (int r = 0; r < 4; ++r)
#pragma unroll
        for (int off = 8; off >= 1; off >>= 1)
          tmax[m][r] = fmaxf(tmax[m][r], __shfl_xor(tmax[m][r], off));

    // ---- T13 defer-max: skip rescale if growth <= THR for all rows ----
    float grow = -1e30f;
#pragma unroll
    for (int m = 0; m < 2; ++m)
#pragma unroll
      for (int r = 0; r < 4; ++r)
        grow = fmaxf(grow, tmax[m][r] - mrun[m][r]);
    if (!__all(grow <= 8.0f)) {
#pragma unroll
      for (int m = 0; m < 2; ++m)
#pragma unroll
        for (int r = 0; r < 4; ++r) {
          const float mnew  = fmaxf(mrun[m][r], tmax[m][r]);
          const float alpha = __expf(mrun[m][r] - mnew);
          mrun[m][r] = mnew;
          lrun[m][r] *= alpha;
#pragma unroll
          for (int d = 0; d < 8; ++d) o[m][d][r] *= alpha;
        }
    }
    // ---- P = exp(S - m), row-sums, stash P to per-wave LDS ----
#pragma unroll
    for (int m = 0; m < 2; ++m) {
      float ls[4] = {0.f, 0.f, 0.f, 0.f};
#pragma unroll
      for (int n = 0; n < 4; ++n)
#pragma unroll
        for (int r = 0; r < 4; ++r) {
          const float pv = __expf(s[m][n][r] - mrun[m][r]);
          s[m][n][r] = pv;
          ls[r] += pv;
        }
#pragma unroll
      for (int r = 0; r < 4; ++r) {
#pragma unroll
        for (int off = 8; off >= 1; off >>= 1) ls[r] += __shfl_xor(ls[r], off);
        lrun[m][r] += ls[r];
      }
#pragma unroll
      for (int n = 0; n < 4; ++n)
#pragma unroll
        for (int r = 0; r < 4; ++r)
          Pl[wid][m * 16 + lg * 4 + r][n * 16 + lr] = f2bf(s[m][n][r]);
    }
    // ---- O += P V ----
#pragma unroll
    for (int ks2 = 0; ks2 < 2; ++ks2) {
      short8 pa[2];
#pragma unroll
      for (int m = 0; m < 2; ++m)
        pa[m] = *(const short8*)&Pl[wid][m * 16 + lr][ks2 * 32 + lg * 8];
      __builtin_amdgcn_s_setprio(1);
#pragma unroll
      for (int dt = 0; dt < 8; ++dt)
#pragma unroll
        for (int m = 0; m < 2; ++m)
          o[m][dt] = MFMA(pa[m], vf[ks2][dt], o[m][dt]);
      __builtin_amdgcn_s_setprio(0);
    }
  }
  // ---- normalize + store to attn-out [B*T, 2048] bf16 ----
#pragma unroll
  for (int m = 0; m < 2; ++m)
#pragma unroll
    for (int r = 0; r < 4; ++r) {
      const float inv = 1.0f / lrun[m][r];
      const int t = qw + m * 16 + lg * 4 + r;
      unsigned short* dst = Ab + ((size_t)(bI * 2048 + t)) * 2048 + h * 128;
#pragma unroll
      for (int dt = 0; dt < 8; ++dt)
        dst[dt * 16 + lr] = f2bf(o[m][dt][r] * inv);
    }
}

extern "C" void kernel_launch(void* const* d_in, const int* in_sizes, int n_in,
                              void* d_out, int out_size, void* d_ws, size_t ws_size,
                              hipStream_t stream) {
  const float* x  = (const float*)d_in[0];
  const float* wq = (const float*)d_in[1];
  const float* bq = (const float*)d_in[2];
  const float* wk = (const float*)d_in[3];
  const float* bk = (const float*)d_in[4];
  const float* wv = (const float*)d_in[5];
  const float* bv = (const float*)d_in[6];
  const float* wo = (const float*)d_in[7];
  const float* bo = (const float*)d_in[8];

  float* out  = (float*)d_out;                 // [B,T,d] fp32
  float* kout = out + (size_t)16777216;        // [B,H,T,hd] fp32
  float* vout = out + (size_t)33554432;        // [B,H,T,hd] fp32

  // workspace layout (bf16 elements)
  unsigned short* xb  = (unsigned short*)d_ws;       // x bf16 [8192,2048]
  unsigned short* wqb = xb  + 16777216;              // wq/wk/wv contiguous = [6144,2048]
  unsigned short* wkb = wqb + 4194304;
  unsigned short* wvb = wkb + 4194304;
  unsigned short* wob = wvb + 4194304;
  unsigned short* Qw  = wob + 4194304;               // Q bf16 fragment-packed
  unsigned short* Kw  = Qw  + 16777216;              // K bf16 fragment-packed
  unsigned short* Vfw = Kw  + 16777216;              // V bf16 V-packed
  unsigned short* Aw  = Vfw + 16777216;              // attn out bf16 [B*T, 2048]

  const int M = 8192, K = 2048;

  cvt_all<<<dim3(256, 8), 256, 0, stream>>>(x, xb, wq, wk, wv, wo,
                                            wqb, wkb, wvb, wob);

  // fused QKV: N = 6144, 24x32 = 768 blocks
  gemm8p<0><<<dim3(768), 512, 0, stream>>>(xb, wqb, bq, bk, bv,
                                           kout, vout, Qw, Kw, Vfw,
                                           nullptr, M, 6144, K);

  attn_fwd<<<dim3(1024), 256, 0, stream>>>(Qw, Kw, Vfw, Aw);

  // out projection: N = 2048, 8x32 = 256 blocks
  gemm8p<3><<<dim3(256), 512, 0, stream>>>(Aw, wob, bo, nullptr, nullptr,
                                           nullptr, nullptr, nullptr, nullptr, nullptr,
                                           out, M, 2048, K);
}

// Round 16
// 481.760 us; speedup vs baseline: 1.0977x; 1.0977x over previous
//
#include <hip/hip_runtime.h>
#include <hip/hip_bf16.h>
#include <stdint.h>

typedef __attribute__((ext_vector_type(8))) short short8;
typedef __attribute__((ext_vector_type(4))) float f32x4;

#define DEVI __device__ __forceinline__

DEVI unsigned short f2bf(float f) {
  union { float f; unsigned int u; } c; c.f = f;
  unsigned int u = c.u;
  u += 0x7fffu + ((u >> 16) & 1u);   // round-to-nearest-even
  return (unsigned short)(u >> 16);
}

DEVI void gl_lds16(const void* gsrc, void* lds) {
  __builtin_amdgcn_global_load_lds(
      (const __attribute__((address_space(1))) unsigned int*)gsrc,
      (__attribute__((address_space(3))) unsigned int*)lds, 16, 0, 0);
}

#define MFMA(a, b, c) __builtin_amdgcn_mfma_f32_16x16x32_bf16((a), (b), (c), 0, 0, 0)
#define BAR()  __builtin_amdgcn_s_barrier()
#define SCHED0() __builtin_amdgcn_sched_barrier(0)

// ---------------- merged fp32 -> bf16 convert: x (4 quarters) + 4 weights ----------------
__global__ void cvt_all(const float* __restrict__ x, unsigned short* __restrict__ xb,
                        const float* __restrict__ w0, const float* __restrict__ w1,
                        const float* __restrict__ w2, const float* __restrict__ w3,
                        unsigned short* __restrict__ o0, unsigned short* __restrict__ o1,
                        unsigned short* __restrict__ o2, unsigned short* __restrict__ o3) {
  const int sel = blockIdx.y;
  const float* in;
  unsigned short* out;
  if (sel < 4) { in = x + (size_t)sel * 4194304; out = xb + (size_t)sel * 4194304; }
  else if (sel == 4) { in = w0; out = o0; }
  else if (sel == 5) { in = w1; out = o1; }
  else if (sel == 6) { in = w2; out = o2; }
  else               { in = w3; out = o3; }
  const int stride = gridDim.x * blockDim.x;
  for (int i = blockIdx.x * blockDim.x + threadIdx.x; i < 1048576; i += stride) {
    const float4 v = ((const float4*)in)[i];
    ushort4 o;
    o.x = f2bf(v.x); o.y = f2bf(v.y); o.z = f2bf(v.z); o.w = f2bf(v.w);
    ((ushort4*)out)[i] = o;
  }
}

// Fragment-packed layouts (per head, T=2048, HD=128, 262144 elems):
//  QK-pack:  off(t,e) = (t>>4)*2048 + (e>>5)*512 + (t&15)*32 + (e&31)
//  V-pack:   off(d,t) = (t>>6)*8192 + (d>>4)*1024 + ((t>>5)&1)*512 + (d&15)*32 + (t&31)

// ---------------- 256x256 8-phase bf16 GEMM ----------------
// bm-major XCD swizzle: XCD k owns bm panels {4k..4k+3} (A live-set 4MB ~ L2)
// x 8 bn panels -> A gets 8x concurrent cross-block reuse, B 4x, instead of
// the old bn-major mapping that swept 32MB of A through each 4MB L2.
template<int MODE>
__global__ __launch_bounds__(512, 2)
void gemm8p(const unsigned short* __restrict__ A,
            const unsigned short* __restrict__ Bw,
            const float* __restrict__ bq,
            const float* __restrict__ bk,
            const float* __restrict__ bv,
            float* __restrict__ Kf,
            float* __restrict__ Vf,
            unsigned short* __restrict__ Qpk,
            unsigned short* __restrict__ Kpk,
            unsigned short* __restrict__ Vpk,
            float* __restrict__ Cf,
            int M, int N, int K)
{
  __shared__ unsigned short S[2][32768];   // per buf: A frags [0,16384), B [16384,32768)
  const int tid  = threadIdx.x;
  const int lane = tid & 63;
  const int wid  = tid >> 6;
  const int l15  = lane & 15, l4 = lane >> 4;
  const int wm   = wid >> 2, wn = wid & 3;

  // bm-major XCD-bijective swizzle (M=8192 -> 32 bm panels, 4 per XCD).
  const int q   = blockIdx.x;
  const int xcd = q & 7;
  const int idx = q >> 3;
  const int bm = (xcd * 4 + (idx & 3)) * 256;
  const int bn = (idx >> 2) * 256;

  const unsigned short* Asrc = A  + (size_t)(bm + (wid >> 1) * 16 + l15) * K + (wid & 1) * 32 + l4 * 8;
  const unsigned short* Bsrc = Bw + (size_t)(bn + (wid >> 1) * 16 + l15) * K + (wid & 1) * 32 + l4 * 8;

  const int nKt   = K >> 6;
  const int HTmax = nKt * 4;

  auto stage_ht = [&](int g) {
    if (g >= HTmax) return;
    const int t = g >> 2, sub = g & 3, buf = t & 1, k0 = t << 6;
#pragma unroll
    for (int cc = 0; cc < 2; ++cc) {
      if (sub >= 2) {
        const int c = (sub - 2) * 2 + cc;
        gl_lds16(Asrc + (size_t)(c * 64) * K + k0,
                 &S[buf][c * 4096 + wid * 512 + lane * 8]);
      } else {
        const int c = sub * 2 + cc;
        gl_lds16(Bsrc + (size_t)(c * 64) * K + k0,
                 &S[buf][16384 + c * 4096 + wid * 512 + lane * 8]);
      }
    }
  };

#pragma unroll
  for (int g = 0; g < 7; ++g) stage_ht(g);
  asm volatile("s_waitcnt vmcnt(6)" ::: "memory");
  SCHED0();
  BAR();

  f32x4 acc[8][4] = {};
  short8 a[4][2], b[4][2];

  for (int t = 0; t < nKt; ++t) {
    const unsigned short* Sb = S[t & 1];
    const int P = t * 4;

#pragma unroll
    for (int i = 0; i < 4; ++i)
#pragma unroll
      for (int ks = 0; ks < 2; ++ks)
        a[i][ks] = *(const short8*)&Sb[((wm * 8 + i) * 2 + ks) * 512 + lane * 8];
#pragma unroll
    for (int j = 0; j < 4; ++j)
#pragma unroll
      for (int ks = 0; ks < 2; ++ks)
        b[j][ks] = *(const short8*)&Sb[16384 + ((wn * 4 + j) * 2 + ks) * 512 + lane * 8];
    stage_ht(P + 7);
    BAR();
    asm volatile("s_waitcnt lgkmcnt(0)" ::: "memory");
    SCHED0();
    __builtin_amdgcn_s_setprio(1);
#pragma unroll
    for (int i = 0; i < 4; ++i)
#pragma unroll
      for (int j = 0; j < 2; ++j)
#pragma unroll
        for (int ks = 0; ks < 2; ++ks)
          acc[i][j] = MFMA(a[i][ks], b[j][ks], acc[i][j]);
    __builtin_amdgcn_s_setprio(0);
    BAR();

    stage_ht(P + 8);
    BAR();
    __builtin_amdgcn_s_setprio(1);
#pragma unroll
    for (int i = 0; i < 4; ++i)
#pragma unroll
      for (int j = 0; j < 2; ++j)
#pragma unroll
        for (int ks = 0; ks < 2; ++ks)
          acc[i][2 + j] = MFMA(a[i][ks], b[2 + j][ks], acc[i][2 + j]);
    __builtin_amdgcn_s_setprio(0);
    BAR();

#pragma unroll
    for (int i = 0; i < 4; ++i)
#pragma unroll
      for (int ks = 0; ks < 2; ++ks)
        a[i][ks] = *(const short8*)&Sb[((wm * 8 + 4 + i) * 2 + ks) * 512 + lane * 8];
    stage_ht(P + 9);
    BAR();
    asm volatile("s_waitcnt lgkmcnt(0)" ::: "memory");
    SCHED0();
    __builtin_amdgcn_s_setprio(1);
#pragma unroll
    for (int i = 0; i < 4; ++i)
#pragma unroll
      for (int j = 0; j < 2; ++j)
#pragma unroll
        for (int ks = 0; ks < 2; ++ks)
          acc[4 + i][j] = MFMA(a[i][ks], b[j][ks], acc[4 + i][j]);
    __builtin_amdgcn_s_setprio(0);
    BAR();

    stage_ht(P + 10);
    if (t < nKt - 2)       { asm volatile("s_waitcnt vmcnt(6)" ::: "memory"); SCHED0(); }
    else if (t == nKt - 2) { asm volatile("s_waitcnt vmcnt(0)" ::: "memory"); SCHED0(); }
    BAR();
    __builtin_amdgcn_s_setprio(1);
#pragma unroll
    for (int i = 0; i < 4; ++i)
#pragma unroll
      for (int j = 0; j < 2; ++j)
#pragma unroll
        for (int ks = 0; ks < 2; ++ks)
          acc[4 + i][2 + j] = MFMA(a[i][ks], b[2 + j][ks], acc[4 + i][2 + j]);
    __builtin_amdgcn_s_setprio(0);
    BAR();
  }

  // ---- epilogue ----
  const int rbase = l4 * 4;
#pragma unroll
  for (int m = 0; m < 8; ++m) {
    const int row0 = bm + wm * 128 + m * 16 + rbase;
#pragma unroll
    for (int n = 0; n < 4; ++n) {
      const int col6 = bn + wn * 64 + n * 16 + l15;
      if constexpr (MODE == 3) {
        const float bb = bq[col6];
#pragma unroll
        for (int r = 0; r < 4; ++r)
          Cf[(size_t)(row0 + r) * N + col6] = acc[m][n][r] + bb;
      } else {
        const int sel = col6 >> 11;
        const int col = col6 & 2047;
        const float bb = (sel == 0 ? bq : sel == 1 ? bk : bv)[col];
        float vv[4];
#pragma unroll
        for (int r = 0; r < 4; ++r) vv[r] = acc[m][n][r] + bb;
        const int bI = row0 >> 11, t0 = row0 & 2047;
        const int h = col >> 7, e = col & 127;
        const size_t hb = ((size_t)(bI * 16 + h)) * 262144;
        if (sel == 0) {
          const size_t qb = hb + (size_t)(t0 >> 4) * 2048 + (e >> 5) * 512
                          + (t0 & 15) * 32 + (e & 31);
#pragma unroll
          for (int r = 0; r < 4; ++r) Qpk[qb + (size_t)r * 32] = f2bf(vv[r]);
        } else if (sel == 1) {
          const size_t idx2 = hb + (size_t)t0 * 128 + e;
          const size_t qb = hb + (size_t)(t0 >> 4) * 2048 + (e >> 5) * 512
                          + (t0 & 15) * 32 + (e & 31);
#pragma unroll
          for (int r = 0; r < 4; ++r) {
            Kf[idx2 + (size_t)r * 128] = vv[r];
            Kpk[qb + (size_t)r * 32] = f2bf(vv[r]);
          }
        } else {
          const size_t idx2 = hb + (size_t)t0 * 128 + e;
#pragma unroll
          for (int r = 0; r < 4; ++r) Vf[idx2 + (size_t)r * 128] = vv[r];
          const size_t vb = hb + (size_t)(t0 >> 6) * 8192 + (size_t)(e >> 4) * 1024
                          + ((t0 >> 5) & 1) * 512 + (e & 15) * 32 + (t0 & 31);
          ushort4 pk;
          pk.x = f2bf(vv[0]); pk.y = f2bf(vv[1]);
          pk.z = f2bf(vv[2]); pk.w = f2bf(vv[3]);
          *(ushort4*)&Vpk[vb] = pk;
        }
      }
    }
  }
}

// ---------------- causal flash attention: strip-paired + defer-max (r14, best) ----------------
// 512 blocks x 256 threads (4 independent waves). Each wave processes TWO
// 32-row q-strips of one head: s = 63-p (heavy) then s = p (light) ->
// tiles/wave = 33 for EVERY p (exact static balance). Barrier-free.
__global__ __launch_bounds__(256, 2)
void attn_fwd(const unsigned short* __restrict__ Qf,
              const unsigned short* __restrict__ Kf,
              const unsigned short* __restrict__ Vf,
              unsigned short* __restrict__ Ab)
{
  constexpr float scale = 0.08838834764831843f;  // 1/sqrt(128)
  __shared__ unsigned short Pl[4][32][72];

  const int bid = blockIdx.x;           // 0..511
  const int xcd = bid & 7;
  const int idx = bid >> 3;             // 0..63
  const int bh  = xcd * 8 + (idx & 7);  // head; same-head blocks share an XCD
  const int prI = idx >> 3;             // 0..7 pair-group
  const int tid = threadIdx.x;
  const int wid = tid >> 6, lane = tid & 63;
  const int p   = prI * 4 + wid;        // 0..31: this wave's strip pair (p, 63-p)
  const int bI = bh >> 4, h = bh & 15;
  const int lr = lane & 15, lg = lane >> 4;
  const int lfo = lr * 32 + lg * 8;     // per-lane offset within 1KB frag

  const unsigned short* Qh = Qf + (size_t)bh * 262144;
  const unsigned short* Kp = Kf + (size_t)bh * 262144;
  const unsigned short* Vp = Vf + (size_t)bh * 262144;

  for (int pass = 0; pass < 2; ++pass) {
    const int strip = pass ? p : (63 - p);     // heavy strip first
    const int qw = strip * 32;
    const unsigned short* Qp = Qh + (size_t)(qw >> 4) * 2048;

    short8 qf[2][4];
#pragma unroll
    for (int m = 0; m < 2; ++m)
#pragma unroll
      for (int ks = 0; ks < 4; ++ks)
        qf[m][ks] = *(const short8*)&Qp[m * 2048 + ks * 512 + lfo];

    f32x4 o[2][8] = {};
    float mrun[2][4], lrun[2][4];
#pragma unroll
    for (int m = 0; m < 2; ++m)
#pragma unroll
      for (int r = 0; r < 4; ++r) { mrun[m][r] = -1e30f; lrun[m][r] = 0.f; }

    const int nfull = qw >> 6;                 // tiles before the diagonal tile
    for (int kt = 0; kt <= nfull; ++kt) {
      const int kv0 = kt * 64;
      const bool diag = (kt == nfull);
      const unsigned short* Kt = Kp + (size_t)(kv0 >> 4) * 2048;
      const unsigned short* Vt = Vp + (size_t)(kv0 >> 6) * 8192;

      // ---- S = Q K^T : 16 coalesced K-frag loads, then 32 MFMA ----
      short8 kf[4][4];
#pragma unroll
      for (int n = 0; n < 4; ++n)
#pragma unroll
        for (int ks = 0; ks < 4; ++ks)
          kf[n][ks] = *(const short8*)&Kt[n * 2048 + ks * 512 + lfo];
      f32x4 s[2][4] = {};
      __builtin_amdgcn_s_setprio(1);
#pragma unroll
      for (int ks = 0; ks < 4; ++ks)
#pragma unroll
        for (int m = 0; m < 2; ++m)
#pragma unroll
          for (int n = 0; n < 4; ++n)
            s[m][n] = MFMA(qf[m][ks], kf[n][ks], s[m][n]);
      __builtin_amdgcn_s_setprio(0);

      // ---- issue all V-frag loads; latency hides under softmax ----
      short8 vf[2][8];
#pragma unroll
      for (int ks2 = 0; ks2 < 2; ++ks2)
#pragma unroll
        for (int dt = 0; dt < 8; ++dt)
          vf[ks2][dt] = *(const short8*)&Vt[dt * 1024 + ks2 * 512 + lfo];

      // ---- scale (+ mask on diagonal tile) + tile row-max ----
      float tmax[2][4];
#pragma unroll
      for (int m = 0; m < 2; ++m)
#pragma unroll
        for (int r = 0; r < 4; ++r) tmax[m][r] = -1e30f;
#pragma unroll
      for (int m = 0; m < 2; ++m)
#pragma unroll
        for (int n = 0; n < 4; ++n) {
          const int kg = kv0 + n * 16 + lr;
#pragma unroll
          for (int r = 0; r < 4; ++r) {
            float sv = s[m][n][r] * scale;
            if (diag) {
              const int qg = qw + m * 16 + lg * 4 + r;
              sv = (kg <= qg) ? sv : -1e30f;
            }
            s[m][n][r] = sv;
            tmax[m][r] = fmaxf(tmax[m][r], sv);
          }
        }
      // ---- reduce tile max across the 16-lane row groups ----
#pragma unroll
      for (int m = 0; m < 2; ++m)
#pragma unroll
        for (int r = 0; r < 4; ++r)
#pragma unroll
          for (int off = 8; off >= 1; off >>= 1)
            tmax[m][r] = fmaxf(tmax[m][r], __shfl_xor(tmax[m][r], off));

      // ---- T13 defer-max: skip rescale if growth <= THR for all rows ----
      float grow = -1e30f;
#pragma unroll
      for (int m = 0; m < 2; ++m)
#pragma unroll
        for (int r = 0; r < 4; ++r)
          grow = fmaxf(grow, tmax[m][r] - mrun[m][r]);
      if (!__all(grow <= 8.0f)) {
#pragma unroll
        for (int m = 0; m < 2; ++m)
#pragma unroll
          for (int r = 0; r < 4; ++r) {
            const float mnew  = fmaxf(mrun[m][r], tmax[m][r]);
            const float alpha = __expf(mrun[m][r] - mnew);
            mrun[m][r] = mnew;
            lrun[m][r] *= alpha;
#pragma unroll
            for (int d = 0; d < 8; ++d) o[m][d][r] *= alpha;
          }
      }
      // ---- P = exp(S - m), row-sums, stash P to per-wave LDS ----
#pragma unroll
      for (int m = 0; m < 2; ++m) {
        float ls[4] = {0.f, 0.f, 0.f, 0.f};
#pragma unroll
        for (int n = 0; n < 4; ++n)
#pragma unroll
          for (int r = 0; r < 4; ++r) {
            const float pv = __expf(s[m][n][r] - mrun[m][r]);
            s[m][n][r] = pv;
            ls[r] += pv;
          }
#pragma unroll
        for (int r = 0; r < 4; ++r) {
#pragma unroll
          for (int off = 8; off >= 1; off >>= 1) ls[r] += __shfl_xor(ls[r], off);
          lrun[m][r] += ls[r];
        }
#pragma unroll
        for (int n = 0; n < 4; ++n)
#pragma unroll
          for (int r = 0; r < 4; ++r)
            Pl[wid][m * 16 + lg * 4 + r][n * 16 + lr] = f2bf(s[m][n][r]);
      }
      // ---- O += P V ----
#pragma unroll
      for (int ks2 = 0; ks2 < 2; ++ks2) {
        short8 pa[2];
#pragma unroll
        for (int m = 0; m < 2; ++m)
          pa[m] = *(const short8*)&Pl[wid][m * 16 + lr][ks2 * 32 + lg * 8];
        __builtin_amdgcn_s_setprio(1);
#pragma unroll
        for (int dt = 0; dt < 8; ++dt)
#pragma unroll
          for (int m = 0; m < 2; ++m)
            o[m][dt] = MFMA(pa[m], vf[ks2][dt], o[m][dt]);
        __builtin_amdgcn_s_setprio(0);
      }
    }
    // ---- normalize + store to attn-out [B*T, 2048] bf16 ----
#pragma unroll
    for (int m = 0; m < 2; ++m)
#pragma unroll
      for (int r = 0; r < 4; ++r) {
        const float inv = 1.0f / lrun[m][r];
        const int t = qw + m * 16 + lg * 4 + r;
        unsigned short* dst = Ab + ((size_t)(bI * 2048 + t)) * 2048 + h * 128;
#pragma unroll
        for (int dt = 0; dt < 8; ++dt)
          dst[dt * 16 + lr] = f2bf(o[m][dt][r] * inv);
      }
  }
}

extern "C" void kernel_launch(void* const* d_in, const int* in_sizes, int n_in,
                              void* d_out, int out_size, void* d_ws, size_t ws_size,
                              hipStream_t stream) {
  const float* x  = (const float*)d_in[0];
  const float* wq = (const float*)d_in[1];
  const float* bq = (const float*)d_in[2];
  const float* wk = (const float*)d_in[3];
  const float* bk = (const float*)d_in[4];
  const float* wv = (const float*)d_in[5];
  const float* bv = (const float*)d_in[6];
  const float* wo = (const float*)d_in[7];
  const float* bo = (const float*)d_in[8];

  float* out  = (float*)d_out;                 // [B,T,d] fp32
  float* kout = out + (size_t)16777216;        // [B,H,T,hd] fp32
  float* vout = out + (size_t)33554432;        // [B,H,T,hd] fp32

  // workspace layout (bf16 elements)
  unsigned short* xb  = (unsigned short*)d_ws;       // x bf16 [8192,2048]
  unsigned short* wqb = xb  + 16777216;              // wq/wk/wv contiguous = [6144,2048]
  unsigned short* wkb = wqb + 4194304;
  unsigned short* wvb = wkb + 4194304;
  unsigned short* wob = wvb + 4194304;
  unsigned short* Qw  = wob + 4194304;               // Q bf16 fragment-packed
  unsigned short* Kw  = Qw  + 16777216;              // K bf16 fragment-packed
  unsigned short* Vfw = Kw  + 16777216;              // V bf16 V-packed
  unsigned short* Aw  = Vfw + 16777216;              // attn out bf16 [B*T, 2048]

  const int M = 8192, K = 2048;

  cvt_all<<<dim3(256, 8), 256, 0, stream>>>(x, xb, wq, wk, wv, wo,
                                            wqb, wkb, wvb, wob);

  // fused QKV: N = 6144, 768 blocks
  gemm8p<0><<<dim3(768), 512, 0, stream>>>(xb, wqb, bq, bk, bv,
                                           kout, vout, Qw, Kw, Vfw,
                                           nullptr, M, 6144, K);

  attn_fwd<<<dim3(512), 256, 0, stream>>>(Qw, Kw, Vfw, Aw);

  // out projection: N = 2048, 256 blocks
  gemm8p<3><<<dim3(256), 512, 0, stream>>>(Aw, wob, bo, nullptr, nullptr,
                                           nullptr, nullptr, nullptr, nullptr, nullptr,
                                           out, M, 2048, K);
}